// Round 4
// baseline (380.552 us; speedup 1.0000x reference)
//
#include <hip/hip_runtime.h>
#include <hip/hip_fp16.h>
#include <utility>
#include <type_traits>

// =====================================================================
// 16-qubit, batch-256 statevector simulator.
//
//  * one workgroup (512 threads) per batch element; state = 65536 c64
//    amplitudes held as fp16 (re,im) pairs: 128 __half2 registers/thread.
//  * CNOT rings are GF(2)-linear index maps -> virtualized into the
//    storage matrix A (s[j] = psi[A j]).  Rings cost nothing; each
//    single-qubit gate on logical bit b becomes a "generalized gate"
//    pairing stored indices j <-> j ^ m with role parity(c & j).
//  * encoding + layer-1 act on |0..0> -> product state built directly.
//  * index layout: j = [local 7 bits][lane 6 bits][wave 3 bits]
//      - mask in local bits  -> in-register pair update
//      - mask in lane bits   -> __shfl_xor exchange
//      - mask in wave bits   -> staged LDS chunk exchange + barriers
//
// R3: R2's counters showed VGPR_Count=128 — the compiler's occupancy
// heuristic targeted 4 waves/EU under __launch_bounds__(512,2) (a MIN,
// not a pin) and spilled the whole S[128] to scratch (75 MB/dispatch
// HBM traffic).  Pin waves/EU to exactly 2 via amdgpu_waves_per_eu(2,2)
// -> 256-VGPR budget, S stays in registers.  (R2's barrier-reduction
// rewrite caused a template-instantiation compile blow-up; reverted.)
// =====================================================================

// ---------------- compile-time GF(2) matrices ----------------
struct M16 { unsigned r[16]; };

constexpr M16 ident() { M16 m{}; for (int i = 0; i < 16; ++i) m.r[i] = 1u << i; return m; }

// Composite index map of ring_of_cnot(step s): new[i] = old[R i].
// wire w <-> bit p = 15-w.  CNOT(i, i+s): pc = 15-i, pt = 15-((i+s)%16);
// map: x_pt ^= x_pc.
constexpr M16 ringm(int s) {
  M16 m = ident();
  for (int i = 15; i >= 0; --i) {
    int pc = 15 - i;
    int pt = 15 - ((i + s) & 15);
    m.r[pt] ^= m.r[pc];
  }
  return m;
}

constexpr M16 mmul(M16 A, M16 B) {   // C = A*B  (C x = A (B x))
  M16 C{};
  for (int p = 0; p < 16; ++p) {
    unsigned v = 0;
    for (int q = 0; q < 16; ++q) if ((A.r[p] >> q) & 1u) v ^= B.r[q];
    C.r[p] = v;
  }
  return C;
}

constexpr M16 minv(M16 A) {          // Gauss-Jordan over GF(2)
  M16 I = ident();
  for (int col = 0; col < 16; ++col) {
    int piv = -1;
    for (int row = col; row < 16; ++row) if ((A.r[row] >> col) & 1u) { piv = row; break; }
    unsigned t = A.r[piv]; A.r[piv] = A.r[col]; A.r[col] = t;
    t = I.r[piv]; I.r[piv] = I.r[col]; I.r[col] = t;
    for (int row = 0; row < 16; ++row)
      if (row != col && ((A.r[row] >> col) & 1u)) { A.r[row] ^= A.r[col]; I.r[row] ^= I.r[col]; }
  }
  return I;
}

constexpr bool meq(M16 a, M16 b) { for (int i = 0; i < 16; ++i) if (a.r[i] != b.r[i]) return false; return true; }
constexpr unsigned colmask(M16 P, int b) { unsigned m = 0; for (int p = 0; p < 16; ++p) m |= ((P.r[p] >> b) & 1u) << p; return m; }
constexpr int popc16(unsigned x) { int c = 0; for (int i = 0; i < 16; ++i) c += (x >> i) & 1; return c; }
constexpr int topbit_pow(unsigned x) { int b = 0; for (int i = 0; i < 16; ++i) if ((x >> i) & 1) b = i; return 1 << b; }

struct Tables { unsigned gm[64]; unsigned gc[64]; unsigned meas[16]; };

constexpr Tables make_tables() {
  Tables T{};
  M16 R1 = ringm(1), R2 = ringm(2);
  // layer k (k=0..3 -> circuit layers 2..5):
  //   P_2 = R1, P_3 = R1^2, P_4 = R1^2 R2, P_5 = R1^2 R2^2
  M16 P0 = R1;
  M16 P1 = mmul(R1, R1);
  M16 P2 = mmul(P1, R2);
  M16 P3 = mmul(P2, R2);
  M16 P[4] = { P0, P1, P2, P3 };
  for (int k = 0; k < 4; ++k) {
    M16 A = minv(P[k]);
    for (int b = 0; b < 16; ++b) {
      T.gm[k * 16 + b] = colmask(P[k], b);  // pair mask (stored-index XOR)
      T.gc[k * 16 + b] = A.r[b];            // role/sign mask
    }
  }
  M16 A5 = minv(P[3]);
  for (int w = 0; w < 16; ++w) T.meas[w] = A5.r[15 - w];  // output col w uses logical bit 15-w
  return T;
}

constexpr Tables TB = make_tables();

constexpr bool check_tables() {
  for (int g = 0; g < 64; ++g) if ((popc16(TB.gm[g] & TB.gc[g]) & 1) != 1) return false;
  if (!meq(mmul(ringm(1), minv(ringm(1))), ident())) return false;
  if (!meq(mmul(ringm(2), minv(ringm(2))), ident())) return false;
  return true;
}
static_assert(check_tables(), "GF(2) table inconsistency");
static_assert(sizeof(__half2) == 4, "half2 size");

// ---------------- small device helpers ----------------
template<int N, int I = 0, typename F>
__device__ __forceinline__ void sfor(F&& f) {
  if constexpr (I < N) {
    f(std::integral_constant<int, I>{});
    sfor<N, I + 1>(static_cast<F&&>(f));
  }
}

__device__ __forceinline__ int h2i(__half2 v) { return __builtin_bit_cast(int, v); }
__device__ __forceinline__ __half2 i2h(int v) { return __builtin_bit_cast(__half2, v); }
__device__ __forceinline__ unsigned h2u(__half2 v) { return __builtin_bit_cast(unsigned, v); }
__device__ __forceinline__ __half2 u2h(unsigned v) { return __builtin_bit_cast(__half2, v); }

__device__ __forceinline__ __half2 hswap(__half2 v) { __half2 r; r.x = v.y; r.y = v.x; return r; }

// y = s[0]*x + s[1]*swap(x) + s[2]*xp + s[3]*swap(xp)   (packed fp16)
__device__ __forceinline__ __half2 updc(__half2 xs, __half2 xp, const __half2 (&s)[4]) {
  __half2 y = __hmul2(s[0], xs);
  y = __hfma2(s[1], hswap(xs), y);
  y = __hfma2(s[2], xp, y);
  y = __hfma2(s[3], hswap(xp), y);
  return y;
}
template<int T>
__device__ __forceinline__ __half2 upd(__half2 xs, __half2 xp,
                                       const __half2 (&s0)[4], const __half2 (&s1)[4]) {
  if constexpr (T) return updc(xs, xp, s1); else return updc(xs, xp, s0);
}

// SU(2) for U = Ry(c) Rz(b) Ry(a):  U = [[al, -conj(be)], [be, conj(al)]]
__device__ __forceinline__ void su2_coeffs(float a, float b, float c,
                                           float& are, float& aim, float& bre, float& bim) {
  float sapc, capc, samc, camc, sb, cb;
  __sincosf((a + c) * 0.5f, &sapc, &capc);
  __sincosf((a - c) * 0.5f, &samc, &camc);
  __sincosf(b * 0.5f, &sb, &cb);
  are = cb * capc;
  aim = -sb * camc;
  bre = cb * sapc;
  bim = sb * samc;
}

__device__ __forceinline__ unsigned pkh2(float lo, float hi) {
  return h2u(__floats2half2_rn(lo, hi));
}

__device__ __forceinline__ float2 cmulf(float2 a, float vr, float vi) {
  return make_float2(a.x * vr - a.y * vi, a.x * vi + a.y * vr);
}

// ---------------- generalized gate application ----------------
template<int G>
__device__ __forceinline__ void apply_gate(__half2 (&S)[128], unsigned tid,
                                           const unsigned* ctab, unsigned* xbuf) {
  constexpr unsigned m  = TB.gm[G];
  constexpr unsigned c  = TB.gc[G];
  constexpr unsigned mL = m & 127u;   // local-bit part of pair mask
  constexpr unsigned mT = m >> 7;     // thread-bit part (lane 0..5, wave 6..8)
  constexpr int      dt = popc16(c & mL) & 1;  // role flip across local part

  // load the two coefficient sets; swap them if this thread's part of the
  // role parity is 1 (then compile-time local parity t indexes the true role)
  __half2 s0[4], s1[4];
  {
    const unsigned f = __popc((c >> 7) & tid) & 1u;
#pragma unroll
    for (int q = 0; q < 4; ++q) {
      const unsigned lo = ctab[G * 8 + q];
      const unsigned hi = ctab[G * 8 + 4 + q];
      s0[q] = u2h(f ? hi : lo);
      s1[q] = u2h(f ? lo : hi);
    }
  }

  if constexpr (mT == 0u) {
    // ---- pure in-register pairs ----  (here m == mL, so dt == 1)
    static_assert(mT != 0u || dt == 1, "register-pair gate must flip role locally");
    constexpr int hb = topbit_pow(mL);
    sfor<64>([&](auto ii) {
      constexpr int i  = decltype(ii)::value;
      constexpr int L0 = ((i & ~(hb - 1)) << 1) | (i & (hb - 1));
      constexpr int L1 = L0 ^ (int)mL;
      constexpr int t  = popc16(c & (unsigned)L0) & 1;
      const __half2 x0 = S[L0], x1 = S[L1];
      S[L0] = upd<t>(x0, x1, s0, s1);
      S[L1] = upd<t ^ dt>(x1, x0, s0, s1);
    });
  } else if constexpr ((m >> 13) == 0u) {
    // ---- lane-crossing: shfl_xor within the wave ----
    if constexpr (mL == 0u) {
      sfor<128>([&](auto ll) {
        constexpr int L = decltype(ll)::value;
        constexpr int t = popc16(c & (unsigned)L) & 1;
        const __half2 xp = i2h(__shfl_xor(h2i(S[L]), (int)mT, 64));
        S[L] = upd<t>(S[L], xp, s0, s1);
      });
    } else {
      constexpr int hb = topbit_pow(mL);
      sfor<64>([&](auto ii) {
        constexpr int i  = decltype(ii)::value;
        constexpr int L0 = ((i & ~(hb - 1)) << 1) | (i & (hb - 1));
        constexpr int L1 = L0 ^ (int)mL;
        constexpr int t  = popc16(c & (unsigned)L0) & 1;
        const __half2 x0 = S[L0], x1 = S[L1];
        const __half2 xp0 = i2h(__shfl_xor(h2i(x1), (int)mT, 64)); // partner's L1 -> my L0
        const __half2 xp1 = i2h(__shfl_xor(h2i(x0), (int)mT, 64)); // partner's L0 -> my L1
        S[L0] = upd<t>(x0, xp0, s0, s1);
        S[L1] = upd<t ^ dt>(x1, xp1, s0, s1);
      });
    }
  } else {
    // ---- wave-crossing: staged LDS exchange ----
    constexpr unsigned hc = mL >> 3;          // chunk-xor (chunks of 8 amps)
    const unsigned ptid = tid ^ mT;
    if constexpr (hc == 0u) {
      // partner amp lives in the same 8-amp chunk
      sfor<16>([&](auto cc) {
        constexpr int cA = decltype(cc)::value;
        sfor<8>([&](auto ss) {
          constexpr int s = decltype(ss)::value;
          xbuf[s * 512 + tid] = h2u(S[cA * 8 + s]);
        });
        __syncthreads();
        sfor<8>([&](auto ss) {
          constexpr int s    = decltype(ss)::value;
          constexpr int L    = cA * 8 + s;
          constexpr int slot = (L ^ (int)mL) & 7;
          constexpr int t    = popc16(c & (unsigned)L) & 1;
          const __half2 xp = u2h(xbuf[slot * 512 + ptid]);
          S[L] = upd<t>(S[L], xp, s0, s1);
        });
        __syncthreads();
      });
    } else {
      constexpr int tb = topbit_pow(hc);
      sfor<16>([&](auto cc) {
        constexpr int cA = decltype(cc)::value;
        if constexpr ((cA & tb) == 0) {        // process chunk pair (cA, cA^hc)
          constexpr int cB = cA ^ (int)hc;
          sfor<8>([&](auto ss) {
            constexpr int s = decltype(ss)::value;
            xbuf[s * 512 + tid]       = h2u(S[cA * 8 + s]);
            xbuf[(8 + s) * 512 + tid] = h2u(S[cB * 8 + s]);
          });
          __syncthreads();
          sfor<8>([&](auto ss) {
            constexpr int s = decltype(ss)::value;
            {
              constexpr int L    = cA * 8 + s;
              constexpr int p    = L ^ (int)mL;       // lives in chunk cB
              constexpr int slot = 8 + (p & 7);
              constexpr int t    = popc16(c & (unsigned)L) & 1;
              const __half2 xp = u2h(xbuf[slot * 512 + ptid]);
              S[L] = upd<t>(S[L], xp, s0, s1);
            }
            {
              constexpr int L    = cB * 8 + s;
              constexpr int p    = L ^ (int)mL;       // lives in chunk cA
              constexpr int slot = p & 7;
              constexpr int t    = popc16(c & (unsigned)L) & 1;
              const __half2 xp = u2h(xbuf[slot * 512 + ptid]);
              S[L] = upd<t>(S[L], xp, s0, s1);
            }
          });
          __syncthreads();
        }
      });
    }
  }
}

// ---------------- main kernel ----------------
// waves_per_eu pinned to (2,2): a 512-thread block is 8 waves = exactly
// 2/SIMD when resident; pinning stops the compiler's occupancy heuristic
// from targeting 4 waves/EU (128 VGPRs) and spilling S[128] to scratch.
__global__ __attribute__((amdgpu_flat_work_group_size(512, 512), amdgpu_waves_per_eu(2, 2)))
void qcir_kernel(const float* __restrict__ inputs, const float* __restrict__ weight,
                 float* __restrict__ out) {
  __shared__ unsigned xbuf[16 * 512];   // 32 KB exchange buffer
  __shared__ unsigned ctab[64 * 8];     // per-gate packed coeff sets (half2 bits)
  __shared__ float4   itab[16];         // per-wire (al, be) after enc+layer1
  __shared__ float    red[8 * 16];      // reduction scratch

  const unsigned tid = threadIdx.x;
  const unsigned b   = blockIdx.x;

  // ---- build coefficient tables ----
  if (tid < 64) {
    const int g = (int)tid;
    const int k = g >> 4;          // 0..3 -> layers 2..5
    const int bb = g & 15;
    const int w = 15 - bb;         // wire for this logical bit
    const int base = 48 * (k + 1) + 3 * w;
    float are, aim, bre, bim;
    su2_coeffs(weight[base], weight[base + 1], weight[base + 2], are, aim, bre, bim);
    // set0 (role 0):  self = al, partner = -conj(be)
    ctab[g * 8 + 0] = pkh2(are, are);
    ctab[g * 8 + 1] = pkh2(-aim, aim);
    ctab[g * 8 + 2] = pkh2(-bre, -bre);
    ctab[g * 8 + 3] = pkh2(-bim, bim);
    // set1 (role 1):  self = conj(al), partner = be
    ctab[g * 8 + 4] = pkh2(are, are);
    ctab[g * 8 + 5] = pkh2(aim, -aim);
    ctab[g * 8 + 6] = pkh2(bre, bre);
    ctab[g * 8 + 7] = pkh2(-bim, bim);
  } else if (tid < 80) {
    const int w = (int)tid - 64;
    const float a = weight[3 * w] + inputs[b * 16 + w];  // encoding Ry fused in
    float are, aim, bre, bim;
    su2_coeffs(a, weight[3 * w + 1], weight[3 * w + 2], are, aim, bre, bim);
    itab[w] = make_float4(are, aim, bre, bim);           // U|0> = (al, be)
  }
  __syncthreads();

  // ---- init: product state after encoding + layer 1  (A1 = I) ----
  __half2 S[128];
  float2 P = make_float2(1.f, 0.f);
#pragma unroll
  for (int p = 7; p <= 15; ++p) {                 // thread-index bits of j
    const int bit = (int)(tid >> (p - 7)) & 1;
    const float4 t = itab[15 - p];
    P = cmulf(P, bit ? t.z : t.x, bit ? t.w : t.y);
  }
  sfor<16>([&](auto hh) {
    constexpr int h = decltype(hh)::value;        // local bits 3..6
    float2 ph = P;
    sfor<4>([&](auto qq) {
      constexpr int q   = decltype(qq)::value;    // p = 3+q
      constexpr int bit = (h >> q) & 1;
      const float4 t = itab[15 - (3 + q)];
      if constexpr (bit) ph = cmulf(ph, t.z, t.w); else ph = cmulf(ph, t.x, t.y);
    });
    sfor<8>([&](auto ll) {
      constexpr int l = decltype(ll)::value;      // local bits 0..2
      float2 pl = ph;
      sfor<3>([&](auto qq) {
        constexpr int q   = decltype(qq)::value;  // p = q
        constexpr int bit = (l >> q) & 1;
        const float4 t = itab[15 - q];
        if constexpr (bit) pl = cmulf(pl, t.z, t.w); else pl = cmulf(pl, t.x, t.y);
      });
      S[h * 8 + l] = __floats2half2_rn(pl.x, pl.y);
    });
  });

  // ---- layers 2..5: 64 generalized gates (rings virtualized) ----
  sfor<64>([&](auto gg) { apply_gate<decltype(gg)::value>(S, tid, ctab, xbuf); });

  // ---- measurement: <Z_w> via signed probability sums ----
  float acc[16];
  sfor<16>([&](auto ww) { acc[decltype(ww)::value] = 0.f; });
  sfor<128>([&](auto ll) {
    constexpr int L = decltype(ll)::value;
    const float re = __low2float(S[L]);
    const float im = __high2float(S[L]);
    const float p = re * re + im * im;
    sfor<16>([&](auto ww) {
      constexpr int w = decltype(ww)::value;
      constexpr int t = popc16(TB.meas[w] & 127u & (unsigned)L) & 1;
      if constexpr (t) acc[w] -= p; else acc[w] += p;
    });
  });
  sfor<16>([&](auto ww) {
    constexpr int w = decltype(ww)::value;
    const unsigned fw = __popc((TB.meas[w] >> 7) & tid) & 1u;
    float z = fw ? -acc[w] : acc[w];
#pragma unroll
    for (int d = 1; d < 64; d <<= 1) z += __shfl_xor(z, d, 64);
    if ((tid & 63u) == 0u) red[(tid >> 6) * 16 + w] = z;
  });
  __syncthreads();
  if (tid < 16) {
    float s = 0.f;
#pragma unroll
    for (int v = 0; v < 8; ++v) s += red[v * 16 + tid];
    out[b * 16 + tid] = 4.f * s;
  }
}

// ---------------- launcher ----------------
extern "C" void kernel_launch(void* const* d_in, const int* in_sizes, int n_in,
                              void* d_out, int out_size, void* d_ws, size_t ws_size,
                              hipStream_t stream) {
  const float* inputs = (const float*)d_in[0];   // (B, 16) f32
  const float* weight = (const float*)d_in[1];   // (240,)  f32
  float* out = (float*)d_out;                    // (B, 16) f32
  const int B = in_sizes[0] / 16;
  qcir_kernel<<<B, 512, 0, stream>>>(inputs, weight, out);
}

// Round 5
// 346.396 us; speedup vs baseline: 1.0986x; 1.0986x over previous
//
#include <hip/hip_runtime.h>
#include <hip/hip_fp16.h>
#include <utility>
#include <type_traits>

// =====================================================================
// 16-qubit, batch-256 statevector simulator.
//
//  * one workgroup (1024 threads) per batch element; state = 65536 c64
//    amplitudes as fp16 (re,im) pairs: 64 __half2 registers per thread.
//  * CNOT rings are GF(2)-linear index maps -> virtualized into the
//    storage matrix (s[j] = psi[A j]); rings cost nothing; each 1q gate
//    becomes a pair update j <-> j^m with role parity(c & j), m/c
//    compile-time constants.
//  * encoding + layer-1 act on |0..0> -> product state built directly.
//  * index layout: j = [local 6 bits][lane 6 bits][wave 4 bits]
//      - mask in local bits  -> in-register pair update
//      - mask in lane bits   -> __shfl_xor exchange
//      - mask in wave bits   -> staged LDS chunk exchange + barriers
//
// R4: R1-R3 counters proved the allocator pins VGPR_Count=128 (4 waves/EU
// point) regardless of launch_bounds / waves_per_eu attributes, spilling
// the 512-thread version's S[128] (≈100 MB scratch HBM traffic per
// dispatch, 280 GB/s latency-bound).  Fix by construction: 1024 threads
// x 64 state regs fits under 128 VGPRs; also 16 waves/CU (was 8) hides
// LDS-exchange latency better.
// =====================================================================

// ---------------- compile-time GF(2) matrices ----------------
struct M16 { unsigned r[16]; };

constexpr M16 ident() { M16 m{}; for (int i = 0; i < 16; ++i) m.r[i] = 1u << i; return m; }

// Composite index map of ring_of_cnot(step s): new[i] = old[R i].
// wire w <-> bit p = 15-w.  CNOT(i, i+s): pc = 15-i, pt = 15-((i+s)%16);
// map: x_pt ^= x_pc.
constexpr M16 ringm(int s) {
  M16 m = ident();
  for (int i = 15; i >= 0; --i) {
    int pc = 15 - i;
    int pt = 15 - ((i + s) & 15);
    m.r[pt] ^= m.r[pc];
  }
  return m;
}

constexpr M16 mmul(M16 A, M16 B) {   // C = A*B
  M16 C{};
  for (int p = 0; p < 16; ++p) {
    unsigned v = 0;
    for (int q = 0; q < 16; ++q) if ((A.r[p] >> q) & 1u) v ^= B.r[q];
    C.r[p] = v;
  }
  return C;
}

constexpr M16 minv(M16 A) {          // Gauss-Jordan over GF(2)
  M16 I = ident();
  for (int col = 0; col < 16; ++col) {
    int piv = -1;
    for (int row = col; row < 16; ++row) if ((A.r[row] >> col) & 1u) { piv = row; break; }
    unsigned t = A.r[piv]; A.r[piv] = A.r[col]; A.r[col] = t;
    t = I.r[piv]; I.r[piv] = I.r[col]; I.r[col] = t;
    for (int row = 0; row < 16; ++row)
      if (row != col && ((A.r[row] >> col) & 1u)) { A.r[row] ^= A.r[col]; I.r[row] ^= I.r[col]; }
  }
  return I;
}

constexpr bool meq(M16 a, M16 b) { for (int i = 0; i < 16; ++i) if (a.r[i] != b.r[i]) return false; return true; }
constexpr unsigned colmask(M16 P, int b) { unsigned m = 0; for (int p = 0; p < 16; ++p) m |= ((P.r[p] >> b) & 1u) << p; return m; }
constexpr int popc16(unsigned x) { int c = 0; for (int i = 0; i < 16; ++i) c += (x >> i) & 1; return c; }
constexpr int topbit_pow(unsigned x) { int b = 0; for (int i = 0; i < 16; ++i) if ((x >> i) & 1) b = i; return 1 << b; }

struct Tables { unsigned gm[64]; unsigned gc[64]; unsigned meas[16]; };

constexpr Tables make_tables() {
  Tables T{};
  M16 R1 = ringm(1), R2 = ringm(2);
  // layer k (k=0..3 -> circuit layers 2..5):
  //   P_2 = R1, P_3 = R1^2, P_4 = R1^2 R2, P_5 = R1^2 R2^2
  M16 P0 = R1;
  M16 P1 = mmul(R1, R1);
  M16 P2 = mmul(P1, R2);
  M16 P3 = mmul(P2, R2);
  M16 P[4] = { P0, P1, P2, P3 };
  for (int k = 0; k < 4; ++k) {
    M16 A = minv(P[k]);
    for (int b = 0; b < 16; ++b) {
      T.gm[k * 16 + b] = colmask(P[k], b);  // pair mask (stored-index XOR)
      T.gc[k * 16 + b] = A.r[b];            // role/sign mask
    }
  }
  M16 A5 = minv(P[3]);
  for (int w = 0; w < 16; ++w) T.meas[w] = A5.r[15 - w];  // output col w uses logical bit 15-w
  return T;
}

constexpr Tables TB = make_tables();

constexpr bool check_tables() {
  for (int g = 0; g < 64; ++g) if ((popc16(TB.gm[g] & TB.gc[g]) & 1) != 1) return false;
  if (!meq(mmul(ringm(1), minv(ringm(1))), ident())) return false;
  if (!meq(mmul(ringm(2), minv(ringm(2))), ident())) return false;
  return true;
}
static_assert(check_tables(), "GF(2) table inconsistency");
static_assert(sizeof(__half2) == 4, "half2 size");

// ---------------- small device helpers ----------------
template<int N, int I = 0, typename F>
__device__ __forceinline__ void sfor(F&& f) {
  if constexpr (I < N) {
    f(std::integral_constant<int, I>{});
    sfor<N, I + 1>(static_cast<F&&>(f));
  }
}

__device__ __forceinline__ int h2i(__half2 v) { return __builtin_bit_cast(int, v); }
__device__ __forceinline__ __half2 i2h(int v) { return __builtin_bit_cast(__half2, v); }
__device__ __forceinline__ unsigned h2u(__half2 v) { return __builtin_bit_cast(unsigned, v); }
__device__ __forceinline__ __half2 u2h(unsigned v) { return __builtin_bit_cast(__half2, v); }

__device__ __forceinline__ __half2 hswap(__half2 v) { __half2 r; r.x = v.y; r.y = v.x; return r; }

// y = s[0]*x + s[1]*swap(x) + s[2]*xp + s[3]*swap(xp)   (packed fp16)
__device__ __forceinline__ __half2 updc(__half2 xs, __half2 xp, const __half2 (&s)[4]) {
  __half2 y = __hmul2(s[0], xs);
  y = __hfma2(s[1], hswap(xs), y);
  y = __hfma2(s[2], xp, y);
  y = __hfma2(s[3], hswap(xp), y);
  return y;
}
template<int T>
__device__ __forceinline__ __half2 upd(__half2 xs, __half2 xp,
                                       const __half2 (&s0)[4], const __half2 (&s1)[4]) {
  if constexpr (T) return updc(xs, xp, s1); else return updc(xs, xp, s0);
}

// SU(2) for U = Ry(c) Rz(b) Ry(a):  U = [[al, -conj(be)], [be, conj(al)]]
__device__ __forceinline__ void su2_coeffs(float a, float b, float c,
                                           float& are, float& aim, float& bre, float& bim) {
  float sapc, capc, samc, camc, sb, cb;
  __sincosf((a + c) * 0.5f, &sapc, &capc);
  __sincosf((a - c) * 0.5f, &samc, &camc);
  __sincosf(b * 0.5f, &sb, &cb);
  are = cb * capc;
  aim = -sb * camc;
  bre = cb * sapc;
  bim = sb * samc;
}

__device__ __forceinline__ unsigned pkh2(float lo, float hi) {
  return h2u(__floats2half2_rn(lo, hi));
}

__device__ __forceinline__ float2 cmulf(float2 a, float vr, float vi) {
  return make_float2(a.x * vr - a.y * vi, a.x * vi + a.y * vr);
}

// ---------------- generalized gate application ----------------
// j = (tid << 6) | L;  L in [0,64): 64 __half2 state regs per thread.
template<int G>
__device__ __forceinline__ void apply_gate(__half2 (&S)[64], unsigned tid,
                                           const unsigned* ctab, unsigned* xbuf) {
  constexpr unsigned m  = TB.gm[G];
  constexpr unsigned c  = TB.gc[G];
  constexpr unsigned mL = m & 63u;    // local-bit part of pair mask
  constexpr unsigned mT = m >> 6;     // thread-bit part (lane bits 0..5, wave 6..9)
  constexpr unsigned mW = m >> 12;    // wave part
  constexpr int      dt = popc16(c & mL) & 1;  // role flip across local part

  // two coefficient sets; pre-swapped by this thread's role-parity part
  __half2 s0[4], s1[4];
  {
    const unsigned f = __popc((c >> 6) & tid) & 1u;
#pragma unroll
    for (int q = 0; q < 4; ++q) {
      const unsigned lo = ctab[G * 8 + q];
      const unsigned hi = ctab[G * 8 + 4 + q];
      s0[q] = u2h(f ? hi : lo);
      s1[q] = u2h(f ? lo : hi);
    }
  }

  if constexpr (mT == 0u) {
    // ---- pure in-register pairs ----  (m == mL -> dt == 1)
    static_assert(mT != 0u || dt == 1, "register-pair gate must flip role locally");
    constexpr int hb = topbit_pow(mL);
    sfor<32>([&](auto ii) {
      constexpr int i  = decltype(ii)::value;
      constexpr int L0 = ((i & ~(hb - 1)) << 1) | (i & (hb - 1));
      constexpr int L1 = L0 ^ (int)mL;
      constexpr int t  = popc16(c & (unsigned)L0) & 1;
      const __half2 x0 = S[L0], x1 = S[L1];
      S[L0] = upd<t>(x0, x1, s0, s1);
      S[L1] = upd<t ^ dt>(x1, x0, s0, s1);
    });
  } else if constexpr (mW == 0u) {
    // ---- lane-crossing: shfl_xor within the wave ----
    if constexpr (mL == 0u) {
      sfor<64>([&](auto ll) {
        constexpr int L = decltype(ll)::value;
        constexpr int t = popc16(c & (unsigned)L) & 1;
        const __half2 xp = i2h(__shfl_xor(h2i(S[L]), (int)mT, 64));
        S[L] = upd<t>(S[L], xp, s0, s1);
      });
    } else {
      constexpr int hb = topbit_pow(mL);
      sfor<32>([&](auto ii) {
        constexpr int i  = decltype(ii)::value;
        constexpr int L0 = ((i & ~(hb - 1)) << 1) | (i & (hb - 1));
        constexpr int L1 = L0 ^ (int)mL;
        constexpr int t  = popc16(c & (unsigned)L0) & 1;
        const __half2 x0 = S[L0], x1 = S[L1];
        const __half2 xp0 = i2h(__shfl_xor(h2i(x1), (int)mT, 64)); // partner's L1 -> my L0
        const __half2 xp1 = i2h(__shfl_xor(h2i(x0), (int)mT, 64)); // partner's L0 -> my L1
        S[L0] = upd<t>(x0, xp0, s0, s1);
        S[L1] = upd<t ^ dt>(x1, xp1, s0, s1);
      });
    }
  } else {
    // ---- wave-crossing: staged LDS exchange (8-slot buffer) ----
    constexpr unsigned hc = mL >> 3;          // chunk-xor (chunks of 8 amps)
    const unsigned ptid = tid ^ mT;
    if constexpr (hc == 0u) {
      // partner amp lives in the same 8-amp chunk (mL < 8)
      sfor<8>([&](auto cc) {
        constexpr int cA = decltype(cc)::value;
        sfor<8>([&](auto ss) {
          constexpr int s = decltype(ss)::value;
          xbuf[s * 1024 + tid] = h2u(S[cA * 8 + s]);
        });
        __syncthreads();
        sfor<8>([&](auto ss) {
          constexpr int s    = decltype(ss)::value;
          constexpr int L    = cA * 8 + s;
          constexpr int slot = s ^ (int)mL;
          constexpr int t    = popc16(c & (unsigned)L) & 1;
          const __half2 xp = u2h(xbuf[slot * 1024 + ptid]);
          S[L] = upd<t>(S[L], xp, s0, s1);
        });
        __syncthreads();
      });
    } else {
      // chunk pairs (cA, cB = cA^hc): stash old cB in regs, stage cA,
      // update cB, stage old cB, update cA.  4 barriers per pair.
      constexpr int tb = topbit_pow(hc);
      sfor<8>([&](auto cc) {
        constexpr int cA = decltype(cc)::value;
        if constexpr ((cA & tb) == 0) {
          constexpr int cB = cA ^ (int)hc;
          __half2 oldB[8];
          sfor<8>([&](auto ss) {
            constexpr int s = decltype(ss)::value;
            oldB[s] = S[cB * 8 + s];
            xbuf[s * 1024 + tid] = h2u(S[cA * 8 + s]);
          });
          __syncthreads();
          sfor<8>([&](auto ss) {
            constexpr int s    = decltype(ss)::value;
            constexpr int L    = cB * 8 + s;
            constexpr int slot = (L ^ (int)mL) & 7;     // partner local in chunk cA
            constexpr int t    = popc16(c & (unsigned)L) & 1;
            const __half2 xp = u2h(xbuf[slot * 1024 + ptid]);
            S[L] = upd<t>(S[L], xp, s0, s1);
          });
          __syncthreads();   // everyone done reading cA staging
          sfor<8>([&](auto ss) {
            constexpr int s = decltype(ss)::value;
            xbuf[s * 1024 + tid] = h2u(oldB[s]);
          });
          __syncthreads();
          sfor<8>([&](auto ss) {
            constexpr int s    = decltype(ss)::value;
            constexpr int L    = cA * 8 + s;
            constexpr int slot = (L ^ (int)mL) & 7;     // partner local in chunk cB
            constexpr int t    = popc16(c & (unsigned)L) & 1;
            const __half2 xp = u2h(xbuf[slot * 1024 + ptid]);
            S[L] = upd<t>(S[L], xp, s0, s1);
          });
          __syncthreads();   // buffer free for next pair/gate
        }
      });
    }
  }
}

// ---------------- main kernel ----------------
// 1024 threads: 64 state regs + ~40 temps < 128 VGPRs (the allocator's
// 4-waves/EU point) -> no spill by construction.
__global__ __launch_bounds__(1024, 4)
void qcir_kernel(const float* __restrict__ inputs, const float* __restrict__ weight,
                 float* __restrict__ out) {
  __shared__ unsigned xbuf[8 * 1024];   // 32 KB exchange buffer
  __shared__ unsigned ctab[64 * 8];     // per-gate packed coeff sets (half2 bits)
  __shared__ float4   itab[16];         // per-wire (al, be) after enc+layer1
  __shared__ float    red[16 * 16];     // reduction scratch (wave x output)

  const unsigned tid = threadIdx.x;
  const unsigned b   = blockIdx.x;

  // ---- build coefficient tables ----
  if (tid < 64) {
    const int g = (int)tid;
    const int k = g >> 4;          // 0..3 -> layers 2..5
    const int bb = g & 15;
    const int w = 15 - bb;         // wire for this logical bit
    const int base = 48 * (k + 1) + 3 * w;
    float are, aim, bre, bim;
    su2_coeffs(weight[base], weight[base + 1], weight[base + 2], are, aim, bre, bim);
    // set0 (role 0):  self = al, partner = -conj(be)
    ctab[g * 8 + 0] = pkh2(are, are);
    ctab[g * 8 + 1] = pkh2(-aim, aim);
    ctab[g * 8 + 2] = pkh2(-bre, -bre);
    ctab[g * 8 + 3] = pkh2(-bim, bim);
    // set1 (role 1):  self = conj(al), partner = be
    ctab[g * 8 + 4] = pkh2(are, are);
    ctab[g * 8 + 5] = pkh2(aim, -aim);
    ctab[g * 8 + 6] = pkh2(bre, bre);
    ctab[g * 8 + 7] = pkh2(-bim, bim);
  } else if (tid < 80) {
    const int w = (int)tid - 64;
    const float a = weight[3 * w] + inputs[b * 16 + w];  // encoding Ry fused in
    float are, aim, bre, bim;
    su2_coeffs(a, weight[3 * w + 1], weight[3 * w + 2], are, aim, bre, bim);
    itab[w] = make_float4(are, aim, bre, bim);           // U|0> = (al, be)
  }
  __syncthreads();

  // ---- init: product state after encoding + layer 1  (A1 = I) ----
  __half2 S[64];
  float2 P = make_float2(1.f, 0.f);
#pragma unroll
  for (int p = 6; p <= 15; ++p) {                 // thread-index bits of j
    const int bit = (int)(tid >> (p - 6)) & 1;
    const float4 t = itab[15 - p];
    P = cmulf(P, bit ? t.z : t.x, bit ? t.w : t.y);
  }
  sfor<8>([&](auto hh) {
    constexpr int h = decltype(hh)::value;        // local bits 3..5
    float2 ph = P;
    sfor<3>([&](auto qq) {
      constexpr int q   = decltype(qq)::value;    // p = 3+q
      constexpr int bit = (h >> q) & 1;
      const float4 t = itab[15 - (3 + q)];
      if constexpr (bit) ph = cmulf(ph, t.z, t.w); else ph = cmulf(ph, t.x, t.y);
    });
    sfor<8>([&](auto ll) {
      constexpr int l = decltype(ll)::value;      // local bits 0..2
      float2 pl = ph;
      sfor<3>([&](auto qq) {
        constexpr int q   = decltype(qq)::value;  // p = q
        constexpr int bit = (l >> q) & 1;
        const float4 t = itab[15 - q];
        if constexpr (bit) pl = cmulf(pl, t.z, t.w); else pl = cmulf(pl, t.x, t.y);
      });
      S[h * 8 + l] = __floats2half2_rn(pl.x, pl.y);
    });
  });

  // ---- layers 2..5: 64 generalized gates (rings virtualized) ----
  sfor<64>([&](auto gg) { apply_gate<decltype(gg)::value>(S, tid, ctab, xbuf); });

  // ---- measurement: <Z_w> via signed probability sums ----
  float acc[16];
  sfor<16>([&](auto ww) { acc[decltype(ww)::value] = 0.f; });
  sfor<64>([&](auto ll) {
    constexpr int L = decltype(ll)::value;
    const float re = __low2float(S[L]);
    const float im = __high2float(S[L]);
    const float p = re * re + im * im;
    sfor<16>([&](auto ww) {
      constexpr int w = decltype(ww)::value;
      constexpr int t = popc16(TB.meas[w] & 63u & (unsigned)L) & 1;
      if constexpr (t) acc[w] -= p; else acc[w] += p;
    });
  });
  sfor<16>([&](auto ww) {
    constexpr int w = decltype(ww)::value;
    const unsigned fw = __popc((TB.meas[w] >> 6) & tid) & 1u;
    float z = fw ? -acc[w] : acc[w];
#pragma unroll
    for (int d = 1; d < 64; d <<= 1) z += __shfl_xor(z, d, 64);
    if ((tid & 63u) == 0u) red[(tid >> 6) * 16 + w] = z;
  });
  __syncthreads();
  if (tid < 16) {
    float s = 0.f;
#pragma unroll
    for (int v = 0; v < 16; ++v) s += red[v * 16 + tid];
    out[b * 16 + tid] = 4.f * s;
  }
}

// ---------------- launcher ----------------
extern "C" void kernel_launch(void* const* d_in, const int* in_sizes, int n_in,
                              void* d_out, int out_size, void* d_ws, size_t ws_size,
                              hipStream_t stream) {
  const float* inputs = (const float*)d_in[0];   // (B, 16) f32
  const float* weight = (const float*)d_in[1];   // (240,)  f32
  float* out = (float*)d_out;                    // (B, 16) f32
  const int B = in_sizes[0] / 16;
  qcir_kernel<<<B, 1024, 0, stream>>>(inputs, weight, out);
}

// Round 6
// 337.124 us; speedup vs baseline: 1.1288x; 1.0275x over previous
//
#include <hip/hip_runtime.h>
#include <hip/hip_fp16.h>
#include <utility>
#include <type_traits>

// =====================================================================
// 16-qubit, batch-256 statevector simulator.
//
//  * one workgroup (1024 threads) per batch element; state = 65536 c64
//    amplitudes as fp16 (re,im) pairs: 64 __half2 registers per thread.
//  * CNOT rings are GF(2)-linear index maps -> virtualized into the
//    storage matrix (s[j] = psi[A j]); rings cost nothing; each 1q gate
//    becomes a pair update j <-> j^m with role parity(c & j), m/c
//    compile-time constants.
//  * encoding + layer-1 act on |0..0> -> product state built directly.
//  * index layout: j = [local 6 bits][lane 6 bits][wave 4 bits]
//      - mask in local bits  -> in-register pair update
//      - mask in lane bits   -> __shfl_xor exchange
//      - mask in wave bits   -> staged LDS chunk exchange + barriers
//
// R6: occupancy model (fits R2/R4/R5 counters exactly): the allocator's
// VGPR budget = 512 / (occupancy implied by LDS+thread limits); attrs
// cannot lower that occupancy.  R5 (36 KB LDS, 1024 thr) implied 2
// blocks/CU -> 8 waves/EU -> 64 VGPRs -> S[64] spilled (87 MB scratch
// HBM traffic).  Fix: make LDS > 80 KB so only 1 block/CU fits ->
// 4 waves/EU -> 128-VGPR budget -> no spill by the allocator's own rule.
// The 64 KB exchange region also halves wave-gate barriers (8/gate).
// =====================================================================

// ---------------- compile-time GF(2) matrices ----------------
struct M16 { unsigned r[16]; };

constexpr M16 ident() { M16 m{}; for (int i = 0; i < 16; ++i) m.r[i] = 1u << i; return m; }

// Composite index map of ring_of_cnot(step s): new[i] = old[R i].
// wire w <-> bit p = 15-w.  CNOT(i, i+s): pc = 15-i, pt = 15-((i+s)%16);
// map: x_pt ^= x_pc.
constexpr M16 ringm(int s) {
  M16 m = ident();
  for (int i = 15; i >= 0; --i) {
    int pc = 15 - i;
    int pt = 15 - ((i + s) & 15);
    m.r[pt] ^= m.r[pc];
  }
  return m;
}

constexpr M16 mmul(M16 A, M16 B) {   // C = A*B
  M16 C{};
  for (int p = 0; p < 16; ++p) {
    unsigned v = 0;
    for (int q = 0; q < 16; ++q) if ((A.r[p] >> q) & 1u) v ^= B.r[q];
    C.r[p] = v;
  }
  return C;
}

constexpr M16 minv(M16 A) {          // Gauss-Jordan over GF(2)
  M16 I = ident();
  for (int col = 0; col < 16; ++col) {
    int piv = -1;
    for (int row = col; row < 16; ++row) if ((A.r[row] >> col) & 1u) { piv = row; break; }
    unsigned t = A.r[piv]; A.r[piv] = A.r[col]; A.r[col] = t;
    t = I.r[piv]; I.r[piv] = I.r[col]; I.r[col] = t;
    for (int row = 0; row < 16; ++row)
      if (row != col && ((A.r[row] >> col) & 1u)) { A.r[row] ^= A.r[col]; I.r[row] ^= I.r[col]; }
  }
  return I;
}

constexpr bool meq(M16 a, M16 b) { for (int i = 0; i < 16; ++i) if (a.r[i] != b.r[i]) return false; return true; }
constexpr unsigned colmask(M16 P, int b) { unsigned m = 0; for (int p = 0; p < 16; ++p) m |= ((P.r[p] >> b) & 1u) << p; return m; }
constexpr int popc16(unsigned x) { int c = 0; for (int i = 0; i < 16; ++i) c += (x >> i) & 1; return c; }
constexpr int topbit_pow(unsigned x) { int b = 0; for (int i = 0; i < 16; ++i) if ((x >> i) & 1) b = i; return 1 << b; }

struct Tables { unsigned gm[64]; unsigned gc[64]; unsigned meas[16]; };

constexpr Tables make_tables() {
  Tables T{};
  M16 R1 = ringm(1), R2 = ringm(2);
  // layer k (k=0..3 -> circuit layers 2..5):
  //   P_2 = R1, P_3 = R1^2, P_4 = R1^2 R2, P_5 = R1^2 R2^2
  M16 P0 = R1;
  M16 P1 = mmul(R1, R1);
  M16 P2 = mmul(P1, R2);
  M16 P3 = mmul(P2, R2);
  M16 P[4] = { P0, P1, P2, P3 };
  for (int k = 0; k < 4; ++k) {
    M16 A = minv(P[k]);
    for (int b = 0; b < 16; ++b) {
      T.gm[k * 16 + b] = colmask(P[k], b);  // pair mask (stored-index XOR)
      T.gc[k * 16 + b] = A.r[b];            // role/sign mask
    }
  }
  M16 A5 = minv(P[3]);
  for (int w = 0; w < 16; ++w) T.meas[w] = A5.r[15 - w];  // output col w uses logical bit 15-w
  return T;
}

constexpr Tables TB = make_tables();

constexpr bool check_tables() {
  for (int g = 0; g < 64; ++g) if ((popc16(TB.gm[g] & TB.gc[g]) & 1) != 1) return false;
  if (!meq(mmul(ringm(1), minv(ringm(1))), ident())) return false;
  if (!meq(mmul(ringm(2), minv(ringm(2))), ident())) return false;
  return true;
}
static_assert(check_tables(), "GF(2) table inconsistency");
static_assert(sizeof(__half2) == 4, "half2 size");

// ---------------- small device helpers ----------------
template<int N, int I = 0, typename F>
__device__ __forceinline__ void sfor(F&& f) {
  if constexpr (I < N) {
    f(std::integral_constant<int, I>{});
    sfor<N, I + 1>(static_cast<F&&>(f));
  }
}

__device__ __forceinline__ int h2i(__half2 v) { return __builtin_bit_cast(int, v); }
__device__ __forceinline__ __half2 i2h(int v) { return __builtin_bit_cast(__half2, v); }
__device__ __forceinline__ unsigned h2u(__half2 v) { return __builtin_bit_cast(unsigned, v); }
__device__ __forceinline__ __half2 u2h(unsigned v) { return __builtin_bit_cast(__half2, v); }

__device__ __forceinline__ __half2 hswap(__half2 v) { __half2 r; r.x = v.y; r.y = v.x; return r; }

// y = s[0]*x + s[1]*swap(x) + s[2]*xp + s[3]*swap(xp)   (packed fp16)
__device__ __forceinline__ __half2 updc(__half2 xs, __half2 xp, const __half2 (&s)[4]) {
  __half2 y = __hmul2(s[0], xs);
  y = __hfma2(s[1], hswap(xs), y);
  y = __hfma2(s[2], xp, y);
  y = __hfma2(s[3], hswap(xp), y);
  return y;
}
template<int T>
__device__ __forceinline__ __half2 upd(__half2 xs, __half2 xp,
                                       const __half2 (&s0)[4], const __half2 (&s1)[4]) {
  if constexpr (T) return updc(xs, xp, s1); else return updc(xs, xp, s0);
}

// SU(2) for U = Ry(c) Rz(b) Ry(a):  U = [[al, -conj(be)], [be, conj(al)]]
__device__ __forceinline__ void su2_coeffs(float a, float b, float c,
                                           float& are, float& aim, float& bre, float& bim) {
  float sapc, capc, samc, camc, sb, cb;
  __sincosf((a + c) * 0.5f, &sapc, &capc);
  __sincosf((a - c) * 0.5f, &samc, &camc);
  __sincosf(b * 0.5f, &sb, &cb);
  are = cb * capc;
  aim = -sb * camc;
  bre = cb * sapc;
  bim = sb * samc;
}

__device__ __forceinline__ unsigned pkh2(float lo, float hi) {
  return h2u(__floats2half2_rn(lo, hi));
}

__device__ __forceinline__ float2 cmulf(float2 a, float vr, float vi) {
  return make_float2(a.x * vr - a.y * vi, a.x * vi + a.y * vr);
}

// ---------------- generalized gate application ----------------
// j = (tid << 6) | L;  L in [0,64): 64 __half2 state regs per thread.
template<int G>
__device__ __forceinline__ void apply_gate(__half2 (&S)[64], unsigned tid,
                                           const unsigned* ctab, unsigned* xbuf) {
  constexpr unsigned m  = TB.gm[G];
  constexpr unsigned c  = TB.gc[G];
  constexpr unsigned mL = m & 63u;    // local-bit part of pair mask
  constexpr unsigned mT = m >> 6;     // thread-bit part (lane bits 0..5, wave 6..9)
  constexpr unsigned mW = m >> 12;    // wave part
  constexpr int      dt = popc16(c & mL) & 1;  // role flip across local part

  // two coefficient sets; pre-swapped by this thread's role-parity part
  __half2 s0[4], s1[4];
  {
    const unsigned f = __popc((c >> 6) & tid) & 1u;
#pragma unroll
    for (int q = 0; q < 4; ++q) {
      const unsigned lo = ctab[G * 8 + q];
      const unsigned hi = ctab[G * 8 + 4 + q];
      s0[q] = u2h(f ? hi : lo);
      s1[q] = u2h(f ? lo : hi);
    }
  }

  if constexpr (mT == 0u) {
    // ---- pure in-register pairs ----  (m == mL -> dt == 1)
    static_assert(mT != 0u || dt == 1, "register-pair gate must flip role locally");
    constexpr int hb = topbit_pow(mL);
    sfor<32>([&](auto ii) {
      constexpr int i  = decltype(ii)::value;
      constexpr int L0 = ((i & ~(hb - 1)) << 1) | (i & (hb - 1));
      constexpr int L1 = L0 ^ (int)mL;
      constexpr int t  = popc16(c & (unsigned)L0) & 1;
      const __half2 x0 = S[L0], x1 = S[L1];
      S[L0] = upd<t>(x0, x1, s0, s1);
      S[L1] = upd<t ^ dt>(x1, x0, s0, s1);
    });
  } else if constexpr (mW == 0u) {
    // ---- lane-crossing: shfl_xor within the wave ----
    if constexpr (mL == 0u) {
      sfor<64>([&](auto ll) {
        constexpr int L = decltype(ll)::value;
        constexpr int t = popc16(c & (unsigned)L) & 1;
        const __half2 xp = i2h(__shfl_xor(h2i(S[L]), (int)mT, 64));
        S[L] = upd<t>(S[L], xp, s0, s1);
      });
    } else {
      constexpr int hb = topbit_pow(mL);
      sfor<32>([&](auto ii) {
        constexpr int i  = decltype(ii)::value;
        constexpr int L0 = ((i & ~(hb - 1)) << 1) | (i & (hb - 1));
        constexpr int L1 = L0 ^ (int)mL;
        constexpr int t  = popc16(c & (unsigned)L0) & 1;
        const __half2 x0 = S[L0], x1 = S[L1];
        const __half2 xp0 = i2h(__shfl_xor(h2i(x1), (int)mT, 64)); // partner's L1 -> my L0
        const __half2 xp1 = i2h(__shfl_xor(h2i(x0), (int)mT, 64)); // partner's L0 -> my L1
        S[L0] = upd<t>(x0, xp0, s0, s1);
        S[L1] = upd<t ^ dt>(x1, xp1, s0, s1);
      });
    }
  } else {
    // ---- wave-crossing: staged LDS exchange, 16 slots (2 chunks) per
    // iteration, 4 iterations x 2 barriers = 8 barriers per gate ----
    constexpr unsigned hc = mL >> 3;          // chunk-xor (chunks of 8 amps)
    const unsigned ptid = tid ^ mT;
    if constexpr (hc == 0u) {
      // partner stays in the same chunk (mL < 8): stage consecutive chunk
      // pairs (2g, 2g+1); partner slot = (L^mL) & 15 within the group.
      sfor<4>([&](auto gg_) {
        constexpr int g = decltype(gg_)::value;
        sfor<16>([&](auto ss) {
          constexpr int s = decltype(ss)::value;
          xbuf[s * 1024 + tid] = h2u(S[g * 16 + s]);
        });
        __syncthreads();
        sfor<16>([&](auto ss) {
          constexpr int s    = decltype(ss)::value;
          constexpr int L    = g * 16 + s;
          constexpr int slot = (L ^ (int)mL) & 15;
          constexpr int t    = popc16(c & (unsigned)L) & 1;
          const __half2 xp = u2h(xbuf[slot * 1024 + ptid]);
          S[L] = upd<t>(S[L], xp, s0, s1);
        });
        __syncthreads();
      });
    } else {
      // chunk pairs (cA, cB = cA^hc): stage both (slots 0-7 = cA,
      // 8-15 = cB), then update both from staged pre-gate values.
      constexpr int tb = topbit_pow(hc);
      sfor<8>([&](auto cc) {
        constexpr int cA = decltype(cc)::value;
        if constexpr ((cA & tb) == 0) {
          constexpr int cB = cA ^ (int)hc;
          sfor<8>([&](auto ss) {
            constexpr int s = decltype(ss)::value;
            xbuf[s * 1024 + tid]       = h2u(S[cA * 8 + s]);
            xbuf[(8 + s) * 1024 + tid] = h2u(S[cB * 8 + s]);
          });
          __syncthreads();
          sfor<8>([&](auto ss) {
            constexpr int s = decltype(ss)::value;
            {
              constexpr int L    = cA * 8 + s;
              constexpr int slot = 8 + ((L ^ (int)mL) & 7);   // partner in cB
              constexpr int t    = popc16(c & (unsigned)L) & 1;
              const __half2 xp = u2h(xbuf[slot * 1024 + ptid]);
              S[L] = upd<t>(S[L], xp, s0, s1);
            }
            {
              constexpr int L    = cB * 8 + s;
              constexpr int slot = (L ^ (int)mL) & 7;         // partner in cA
              constexpr int t    = popc16(c & (unsigned)L) & 1;
              const __half2 xp = u2h(xbuf[slot * 1024 + ptid]);
              S[L] = upd<t>(S[L], xp, s0, s1);
            }
          });
          __syncthreads();
        }
      });
    }
  }
}

// ---------------- main kernel ----------------
// LDS deliberately > 80 KB: only 1 block/CU fits -> implied occupancy
// 16 waves/CU = 4 waves/EU -> the allocator's VGPR budget is 128 ->
// S[64] + temps (~100) stays in registers (no spill by construction
// of the allocator's own occupancy rule; see R2/R4/R5 counter table).
__global__ __launch_bounds__(1024, 4)
void qcir_kernel(const float* __restrict__ inputs, const float* __restrict__ weight,
                 float* __restrict__ out) {
  __shared__ unsigned xbuf[24 * 1024];  // 96 KB; 16 slot-rows used for exchange
  __shared__ unsigned ctab[64 * 8];     // per-gate packed coeff sets (half2 bits)
  __shared__ float4   itab[16];         // per-wire (al, be) after enc+layer1
  __shared__ float    red[16 * 16];     // reduction scratch (wave x output)

  const unsigned tid = threadIdx.x;
  const unsigned b   = blockIdx.x;

  // ---- build coefficient tables ----
  if (tid < 64) {
    const int g = (int)tid;
    const int k = g >> 4;          // 0..3 -> layers 2..5
    const int bb = g & 15;
    const int w = 15 - bb;         // wire for this logical bit
    const int base = 48 * (k + 1) + 3 * w;
    float are, aim, bre, bim;
    su2_coeffs(weight[base], weight[base + 1], weight[base + 2], are, aim, bre, bim);
    // set0 (role 0):  self = al, partner = -conj(be)
    ctab[g * 8 + 0] = pkh2(are, are);
    ctab[g * 8 + 1] = pkh2(-aim, aim);
    ctab[g * 8 + 2] = pkh2(-bre, -bre);
    ctab[g * 8 + 3] = pkh2(-bim, bim);
    // set1 (role 1):  self = conj(al), partner = be
    ctab[g * 8 + 4] = pkh2(are, are);
    ctab[g * 8 + 5] = pkh2(aim, -aim);
    ctab[g * 8 + 6] = pkh2(bre, bre);
    ctab[g * 8 + 7] = pkh2(-bim, bim);
  } else if (tid < 80) {
    const int w = (int)tid - 64;
    const float a = weight[3 * w] + inputs[b * 16 + w];  // encoding Ry fused in
    float are, aim, bre, bim;
    su2_coeffs(a, weight[3 * w + 1], weight[3 * w + 2], are, aim, bre, bim);
    itab[w] = make_float4(are, aim, bre, bim);           // U|0> = (al, be)
  }
  __syncthreads();

  // ---- init: product state after encoding + layer 1  (A1 = I) ----
  __half2 S[64];
  float2 P = make_float2(1.f, 0.f);
#pragma unroll
  for (int p = 6; p <= 15; ++p) {                 // thread-index bits of j
    const int bit = (int)(tid >> (p - 6)) & 1;
    const float4 t = itab[15 - p];
    P = cmulf(P, bit ? t.z : t.x, bit ? t.w : t.y);
  }
  sfor<8>([&](auto hh) {
    constexpr int h = decltype(hh)::value;        // local bits 3..5
    float2 ph = P;
    sfor<3>([&](auto qq) {
      constexpr int q   = decltype(qq)::value;    // p = 3+q
      constexpr int bit = (h >> q) & 1;
      const float4 t = itab[15 - (3 + q)];
      if constexpr (bit) ph = cmulf(ph, t.z, t.w); else ph = cmulf(ph, t.x, t.y);
    });
    sfor<8>([&](auto ll) {
      constexpr int l = decltype(ll)::value;      // local bits 0..2
      float2 pl = ph;
      sfor<3>([&](auto qq) {
        constexpr int q   = decltype(qq)::value;  // p = q
        constexpr int bit = (l >> q) & 1;
        const float4 t = itab[15 - q];
        if constexpr (bit) pl = cmulf(pl, t.z, t.w); else pl = cmulf(pl, t.x, t.y);
      });
      S[h * 8 + l] = __floats2half2_rn(pl.x, pl.y);
    });
  });

  // ---- layers 2..5: 64 generalized gates (rings virtualized) ----
  sfor<64>([&](auto gg) { apply_gate<decltype(gg)::value>(S, tid, ctab, xbuf); });

  // ---- measurement: <Z_w> via signed probability sums ----
  float acc[16];
  sfor<16>([&](auto ww) { acc[decltype(ww)::value] = 0.f; });
  sfor<64>([&](auto ll) {
    constexpr int L = decltype(ll)::value;
    const float re = __low2float(S[L]);
    const float im = __high2float(S[L]);
    const float p = re * re + im * im;
    sfor<16>([&](auto ww) {
      constexpr int w = decltype(ww)::value;
      constexpr int t = popc16(TB.meas[w] & 63u & (unsigned)L) & 1;
      if constexpr (t) acc[w] -= p; else acc[w] += p;
    });
  });
  sfor<16>([&](auto ww) {
    constexpr int w = decltype(ww)::value;
    const unsigned fw = __popc((TB.meas[w] >> 6) & tid) & 1u;
    float z = fw ? -acc[w] : acc[w];
#pragma unroll
    for (int d = 1; d < 64; d <<= 1) z += __shfl_xor(z, d, 64);
    if ((tid & 63u) == 0u) red[(tid >> 6) * 16 + w] = z;
  });
  __syncthreads();
  if (tid < 16) {
    float s = 0.f;
#pragma unroll
    for (int v = 0; v < 16; ++v) s += red[v * 16 + tid];
    out[b * 16 + tid] = 4.f * s;
  }
}

// ---------------- launcher ----------------
extern "C" void kernel_launch(void* const* d_in, const int* in_sizes, int n_in,
                              void* d_out, int out_size, void* d_ws, size_t ws_size,
                              hipStream_t stream) {
  const float* inputs = (const float*)d_in[0];   // (B, 16) f32
  const float* weight = (const float*)d_in[1];   // (240,)  f32
  float* out = (float*)d_out;                    // (B, 16) f32
  const int B = in_sizes[0] / 16;
  qcir_kernel<<<B, 1024, 0, stream>>>(inputs, weight, out);
}

// Round 7
// 336.160 us; speedup vs baseline: 1.1321x; 1.0029x over previous
//
#include <hip/hip_runtime.h>
#include <hip/hip_fp16.h>
#include <utility>
#include <type_traits>

// =====================================================================
// 16-qubit, batch-256 statevector simulator.
//
//  * one workgroup (1024 threads) per batch element; state = 65536 c64
//    amplitudes as fp16 (re,im) pairs: 64 __half2 registers per thread.
//  * CNOT rings are GF(2)-linear index maps -> virtualized into the
//    storage matrix (s[j] = psi[A j]); rings cost nothing; each 1q gate
//    becomes a pair update j <-> j^m with role parity(c & j), m/c
//    compile-time constants.
//  * encoding + layer-1 act on |0..0> -> product state built directly.
//  * index layout: j = [local 6 bits][lane 6 bits][wave 4 bits]
//      - mask in local bits  -> in-register pair update
//      - mask in lane bits   -> __shfl_xor exchange
//      - mask in wave bits   -> staged LDS chunk exchange + barriers
//
// R7: R6 proved the allocator ignores occupancy-shaping (LDS 99.5 KB ->
// 1 block/CU, yet VGPR_Count stayed 64 and S[64] spilled ~1.3 GB of
// scratch churn).  New lever: amdgpu_num_vgpr(128) sets the backend's
// budget DIRECTLY (not via occupancy); with waves_per_eu(4,4) the
// request is exactly the legal max, so it cannot be dropped as
// incompatible.  Everything else identical to R6 (one-variable test).
// =====================================================================

// ---------------- compile-time GF(2) matrices ----------------
struct M16 { unsigned r[16]; };

constexpr M16 ident() { M16 m{}; for (int i = 0; i < 16; ++i) m.r[i] = 1u << i; return m; }

// Composite index map of ring_of_cnot(step s): new[i] = old[R i].
// wire w <-> bit p = 15-w.  CNOT(i, i+s): pc = 15-i, pt = 15-((i+s)%16);
// map: x_pt ^= x_pc.
constexpr M16 ringm(int s) {
  M16 m = ident();
  for (int i = 15; i >= 0; --i) {
    int pc = 15 - i;
    int pt = 15 - ((i + s) & 15);
    m.r[pt] ^= m.r[pc];
  }
  return m;
}

constexpr M16 mmul(M16 A, M16 B) {   // C = A*B
  M16 C{};
  for (int p = 0; p < 16; ++p) {
    unsigned v = 0;
    for (int q = 0; q < 16; ++q) if ((A.r[p] >> q) & 1u) v ^= B.r[q];
    C.r[p] = v;
  }
  return C;
}

constexpr M16 minv(M16 A) {          // Gauss-Jordan over GF(2)
  M16 I = ident();
  for (int col = 0; col < 16; ++col) {
    int piv = -1;
    for (int row = col; row < 16; ++row) if ((A.r[row] >> col) & 1u) { piv = row; break; }
    unsigned t = A.r[piv]; A.r[piv] = A.r[col]; A.r[col] = t;
    t = I.r[piv]; I.r[piv] = I.r[col]; I.r[col] = t;
    for (int row = 0; row < 16; ++row)
      if (row != col && ((A.r[row] >> col) & 1u)) { A.r[row] ^= A.r[col]; I.r[row] ^= I.r[col]; }
  }
  return I;
}

constexpr bool meq(M16 a, M16 b) { for (int i = 0; i < 16; ++i) if (a.r[i] != b.r[i]) return false; return true; }
constexpr unsigned colmask(M16 P, int b) { unsigned m = 0; for (int p = 0; p < 16; ++p) m |= ((P.r[p] >> b) & 1u) << p; return m; }
constexpr int popc16(unsigned x) { int c = 0; for (int i = 0; i < 16; ++i) c += (x >> i) & 1; return c; }
constexpr int topbit_pow(unsigned x) { int b = 0; for (int i = 0; i < 16; ++i) if ((x >> i) & 1) b = i; return 1 << b; }

struct Tables { unsigned gm[64]; unsigned gc[64]; unsigned meas[16]; };

constexpr Tables make_tables() {
  Tables T{};
  M16 R1 = ringm(1), R2 = ringm(2);
  // layer k (k=0..3 -> circuit layers 2..5):
  //   P_2 = R1, P_3 = R1^2, P_4 = R1^2 R2, P_5 = R1^2 R2^2
  M16 P0 = R1;
  M16 P1 = mmul(R1, R1);
  M16 P2 = mmul(P1, R2);
  M16 P3 = mmul(P2, R2);
  M16 P[4] = { P0, P1, P2, P3 };
  for (int k = 0; k < 4; ++k) {
    M16 A = minv(P[k]);
    for (int b = 0; b < 16; ++b) {
      T.gm[k * 16 + b] = colmask(P[k], b);  // pair mask (stored-index XOR)
      T.gc[k * 16 + b] = A.r[b];            // role/sign mask
    }
  }
  M16 A5 = minv(P[3]);
  for (int w = 0; w < 16; ++w) T.meas[w] = A5.r[15 - w];  // output col w uses logical bit 15-w
  return T;
}

constexpr Tables TB = make_tables();

constexpr bool check_tables() {
  for (int g = 0; g < 64; ++g) if ((popc16(TB.gm[g] & TB.gc[g]) & 1) != 1) return false;
  if (!meq(mmul(ringm(1), minv(ringm(1))), ident())) return false;
  if (!meq(mmul(ringm(2), minv(ringm(2))), ident())) return false;
  return true;
}
static_assert(check_tables(), "GF(2) table inconsistency");
static_assert(sizeof(__half2) == 4, "half2 size");

// ---------------- small device helpers ----------------
template<int N, int I = 0, typename F>
__device__ __forceinline__ void sfor(F&& f) {
  if constexpr (I < N) {
    f(std::integral_constant<int, I>{});
    sfor<N, I + 1>(static_cast<F&&>(f));
  }
}

__device__ __forceinline__ int h2i(__half2 v) { return __builtin_bit_cast(int, v); }
__device__ __forceinline__ __half2 i2h(int v) { return __builtin_bit_cast(__half2, v); }
__device__ __forceinline__ unsigned h2u(__half2 v) { return __builtin_bit_cast(unsigned, v); }
__device__ __forceinline__ __half2 u2h(unsigned v) { return __builtin_bit_cast(__half2, v); }

__device__ __forceinline__ __half2 hswap(__half2 v) { __half2 r; r.x = v.y; r.y = v.x; return r; }

// y = s[0]*x + s[1]*swap(x) + s[2]*xp + s[3]*swap(xp)   (packed fp16)
__device__ __forceinline__ __half2 updc(__half2 xs, __half2 xp, const __half2 (&s)[4]) {
  __half2 y = __hmul2(s[0], xs);
  y = __hfma2(s[1], hswap(xs), y);
  y = __hfma2(s[2], xp, y);
  y = __hfma2(s[3], hswap(xp), y);
  return y;
}
template<int T>
__device__ __forceinline__ __half2 upd(__half2 xs, __half2 xp,
                                       const __half2 (&s0)[4], const __half2 (&s1)[4]) {
  if constexpr (T) return updc(xs, xp, s1); else return updc(xs, xp, s0);
}

// SU(2) for U = Ry(c) Rz(b) Ry(a):  U = [[al, -conj(be)], [be, conj(al)]]
__device__ __forceinline__ void su2_coeffs(float a, float b, float c,
                                           float& are, float& aim, float& bre, float& bim) {
  float sapc, capc, samc, camc, sb, cb;
  __sincosf((a + c) * 0.5f, &sapc, &capc);
  __sincosf((a - c) * 0.5f, &samc, &camc);
  __sincosf(b * 0.5f, &sb, &cb);
  are = cb * capc;
  aim = -sb * camc;
  bre = cb * sapc;
  bim = sb * samc;
}

__device__ __forceinline__ unsigned pkh2(float lo, float hi) {
  return h2u(__floats2half2_rn(lo, hi));
}

__device__ __forceinline__ float2 cmulf(float2 a, float vr, float vi) {
  return make_float2(a.x * vr - a.y * vi, a.x * vi + a.y * vr);
}

// ---------------- generalized gate application ----------------
// j = (tid << 6) | L;  L in [0,64): 64 __half2 state regs per thread.
template<int G>
__device__ __forceinline__ void apply_gate(__half2 (&S)[64], unsigned tid,
                                           const unsigned* ctab, unsigned* xbuf) {
  constexpr unsigned m  = TB.gm[G];
  constexpr unsigned c  = TB.gc[G];
  constexpr unsigned mL = m & 63u;    // local-bit part of pair mask
  constexpr unsigned mT = m >> 6;     // thread-bit part (lane bits 0..5, wave 6..9)
  constexpr unsigned mW = m >> 12;    // wave part
  constexpr int      dt = popc16(c & mL) & 1;  // role flip across local part

  // two coefficient sets; pre-swapped by this thread's role-parity part
  __half2 s0[4], s1[4];
  {
    const unsigned f = __popc((c >> 6) & tid) & 1u;
#pragma unroll
    for (int q = 0; q < 4; ++q) {
      const unsigned lo = ctab[G * 8 + q];
      const unsigned hi = ctab[G * 8 + 4 + q];
      s0[q] = u2h(f ? hi : lo);
      s1[q] = u2h(f ? lo : hi);
    }
  }

  if constexpr (mT == 0u) {
    // ---- pure in-register pairs ----  (m == mL -> dt == 1)
    static_assert(mT != 0u || dt == 1, "register-pair gate must flip role locally");
    constexpr int hb = topbit_pow(mL);
    sfor<32>([&](auto ii) {
      constexpr int i  = decltype(ii)::value;
      constexpr int L0 = ((i & ~(hb - 1)) << 1) | (i & (hb - 1));
      constexpr int L1 = L0 ^ (int)mL;
      constexpr int t  = popc16(c & (unsigned)L0) & 1;
      const __half2 x0 = S[L0], x1 = S[L1];
      S[L0] = upd<t>(x0, x1, s0, s1);
      S[L1] = upd<t ^ dt>(x1, x0, s0, s1);
    });
  } else if constexpr (mW == 0u) {
    // ---- lane-crossing: shfl_xor within the wave ----
    if constexpr (mL == 0u) {
      sfor<64>([&](auto ll) {
        constexpr int L = decltype(ll)::value;
        constexpr int t = popc16(c & (unsigned)L) & 1;
        const __half2 xp = i2h(__shfl_xor(h2i(S[L]), (int)mT, 64));
        S[L] = upd<t>(S[L], xp, s0, s1);
      });
    } else {
      constexpr int hb = topbit_pow(mL);
      sfor<32>([&](auto ii) {
        constexpr int i  = decltype(ii)::value;
        constexpr int L0 = ((i & ~(hb - 1)) << 1) | (i & (hb - 1));
        constexpr int L1 = L0 ^ (int)mL;
        constexpr int t  = popc16(c & (unsigned)L0) & 1;
        const __half2 x0 = S[L0], x1 = S[L1];
        const __half2 xp0 = i2h(__shfl_xor(h2i(x1), (int)mT, 64)); // partner's L1 -> my L0
        const __half2 xp1 = i2h(__shfl_xor(h2i(x0), (int)mT, 64)); // partner's L0 -> my L1
        S[L0] = upd<t>(x0, xp0, s0, s1);
        S[L1] = upd<t ^ dt>(x1, xp1, s0, s1);
      });
    }
  } else {
    // ---- wave-crossing: staged LDS exchange, 16 slots (2 chunks) per
    // iteration, 4 iterations x 2 barriers = 8 barriers per gate ----
    constexpr unsigned hc = mL >> 3;          // chunk-xor (chunks of 8 amps)
    const unsigned ptid = tid ^ mT;
    if constexpr (hc == 0u) {
      // partner stays in the same chunk (mL < 8): stage consecutive chunk
      // pairs (2g, 2g+1); partner slot = (L^mL) & 15 within the group.
      sfor<4>([&](auto gg_) {
        constexpr int g = decltype(gg_)::value;
        sfor<16>([&](auto ss) {
          constexpr int s = decltype(ss)::value;
          xbuf[s * 1024 + tid] = h2u(S[g * 16 + s]);
        });
        __syncthreads();
        sfor<16>([&](auto ss) {
          constexpr int s    = decltype(ss)::value;
          constexpr int L    = g * 16 + s;
          constexpr int slot = (L ^ (int)mL) & 15;
          constexpr int t    = popc16(c & (unsigned)L) & 1;
          const __half2 xp = u2h(xbuf[slot * 1024 + ptid]);
          S[L] = upd<t>(S[L], xp, s0, s1);
        });
        __syncthreads();
      });
    } else {
      // chunk pairs (cA, cB = cA^hc): stage both (slots 0-7 = cA,
      // 8-15 = cB), then update both from staged pre-gate values.
      constexpr int tb = topbit_pow(hc);
      sfor<8>([&](auto cc) {
        constexpr int cA = decltype(cc)::value;
        if constexpr ((cA & tb) == 0) {
          constexpr int cB = cA ^ (int)hc;
          sfor<8>([&](auto ss) {
            constexpr int s = decltype(ss)::value;
            xbuf[s * 1024 + tid]       = h2u(S[cA * 8 + s]);
            xbuf[(8 + s) * 1024 + tid] = h2u(S[cB * 8 + s]);
          });
          __syncthreads();
          sfor<8>([&](auto ss) {
            constexpr int s = decltype(ss)::value;
            {
              constexpr int L    = cA * 8 + s;
              constexpr int slot = 8 + ((L ^ (int)mL) & 7);   // partner in cB
              constexpr int t    = popc16(c & (unsigned)L) & 1;
              const __half2 xp = u2h(xbuf[slot * 1024 + ptid]);
              S[L] = upd<t>(S[L], xp, s0, s1);
            }
            {
              constexpr int L    = cB * 8 + s;
              constexpr int slot = (L ^ (int)mL) & 7;         // partner in cA
              constexpr int t    = popc16(c & (unsigned)L) & 1;
              const __half2 xp = u2h(xbuf[slot * 1024 + ptid]);
              S[L] = upd<t>(S[L], xp, s0, s1);
            }
          });
          __syncthreads();
        }
      });
    }
  }
}

// ---------------- main kernel ----------------
// amdgpu_num_vgpr(128): sets the backend's VGPR budget directly (the
// occupancy-shaping attributes of R4/R6 were ignored; the heuristic kept
// choosing 64 for 1024-thread kernels and spilling S[64]).  With
// waves_per_eu(4,4), 128 = 512/4 is exactly the legal maximum, so the
// request is compatible and must be honored.  LDS stays > 80 KB (1
// block/CU, matches the 4-waves/EU register point; also 8 barriers per
// wave-crossing gate via the 16-slot exchange).
__global__ __attribute__((amdgpu_flat_work_group_size(1024, 1024),
                          amdgpu_waves_per_eu(4, 4),
                          amdgpu_num_vgpr(128)))
void qcir_kernel(const float* __restrict__ inputs, const float* __restrict__ weight,
                 float* __restrict__ out) {
  __shared__ unsigned xbuf[24 * 1024];  // 96 KB; 16 slot-rows used for exchange
  __shared__ unsigned ctab[64 * 8];     // per-gate packed coeff sets (half2 bits)
  __shared__ float4   itab[16];         // per-wire (al, be) after enc+layer1
  __shared__ float    red[16 * 16];     // reduction scratch (wave x output)

  const unsigned tid = threadIdx.x;
  const unsigned b   = blockIdx.x;

  // ---- build coefficient tables ----
  if (tid < 64) {
    const int g = (int)tid;
    const int k = g >> 4;          // 0..3 -> layers 2..5
    const int bb = g & 15;
    const int w = 15 - bb;         // wire for this logical bit
    const int base = 48 * (k + 1) + 3 * w;
    float are, aim, bre, bim;
    su2_coeffs(weight[base], weight[base + 1], weight[base + 2], are, aim, bre, bim);
    // set0 (role 0):  self = al, partner = -conj(be)
    ctab[g * 8 + 0] = pkh2(are, are);
    ctab[g * 8 + 1] = pkh2(-aim, aim);
    ctab[g * 8 + 2] = pkh2(-bre, -bre);
    ctab[g * 8 + 3] = pkh2(-bim, bim);
    // set1 (role 1):  self = conj(al), partner = be
    ctab[g * 8 + 4] = pkh2(are, are);
    ctab[g * 8 + 5] = pkh2(aim, -aim);
    ctab[g * 8 + 6] = pkh2(bre, bre);
    ctab[g * 8 + 7] = pkh2(-bim, bim);
  } else if (tid < 80) {
    const int w = (int)tid - 64;
    const float a = weight[3 * w] + inputs[b * 16 + w];  // encoding Ry fused in
    float are, aim, bre, bim;
    su2_coeffs(a, weight[3 * w + 1], weight[3 * w + 2], are, aim, bre, bim);
    itab[w] = make_float4(are, aim, bre, bim);           // U|0> = (al, be)
  }
  __syncthreads();

  // ---- init: product state after encoding + layer 1  (A1 = I) ----
  __half2 S[64];
  float2 P = make_float2(1.f, 0.f);
#pragma unroll
  for (int p = 6; p <= 15; ++p) {                 // thread-index bits of j
    const int bit = (int)(tid >> (p - 6)) & 1;
    const float4 t = itab[15 - p];
    P = cmulf(P, bit ? t.z : t.x, bit ? t.w : t.y);
  }
  sfor<8>([&](auto hh) {
    constexpr int h = decltype(hh)::value;        // local bits 3..5
    float2 ph = P;
    sfor<3>([&](auto qq) {
      constexpr int q   = decltype(qq)::value;    // p = 3+q
      constexpr int bit = (h >> q) & 1;
      const float4 t = itab[15 - (3 + q)];
      if constexpr (bit) ph = cmulf(ph, t.z, t.w); else ph = cmulf(ph, t.x, t.y);
    });
    sfor<8>([&](auto ll) {
      constexpr int l = decltype(ll)::value;      // local bits 0..2
      float2 pl = ph;
      sfor<3>([&](auto qq) {
        constexpr int q   = decltype(qq)::value;  // p = q
        constexpr int bit = (l >> q) & 1;
        const float4 t = itab[15 - q];
        if constexpr (bit) pl = cmulf(pl, t.z, t.w); else pl = cmulf(pl, t.x, t.y);
      });
      S[h * 8 + l] = __floats2half2_rn(pl.x, pl.y);
    });
  });

  // ---- layers 2..5: 64 generalized gates (rings virtualized) ----
  sfor<64>([&](auto gg) { apply_gate<decltype(gg)::value>(S, tid, ctab, xbuf); });

  // ---- measurement: <Z_w> via signed probability sums ----
  float acc[16];
  sfor<16>([&](auto ww) { acc[decltype(ww)::value] = 0.f; });
  sfor<64>([&](auto ll) {
    constexpr int L = decltype(ll)::value;
    const float re = __low2float(S[L]);
    const float im = __high2float(S[L]);
    const float p = re * re + im * im;
    sfor<16>([&](auto ww) {
      constexpr int w = decltype(ww)::value;
      constexpr int t = popc16(TB.meas[w] & 63u & (unsigned)L) & 1;
      if constexpr (t) acc[w] -= p; else acc[w] += p;
    });
  });
  sfor<16>([&](auto ww) {
    constexpr int w = decltype(ww)::value;
    const unsigned fw = __popc((TB.meas[w] >> 6) & tid) & 1u;
    float z = fw ? -acc[w] : acc[w];
#pragma unroll
    for (int d = 1; d < 64; d <<= 1) z += __shfl_xor(z, d, 64);
    if ((tid & 63u) == 0u) red[(tid >> 6) * 16 + w] = z;
  });
  __syncthreads();
  if (tid < 16) {
    float s = 0.f;
#pragma unroll
    for (int v = 0; v < 16; ++v) s += red[v * 16 + tid];
    out[b * 16 + tid] = 4.f * s;
  }
}

// ---------------- launcher ----------------
extern "C" void kernel_launch(void* const* d_in, const int* in_sizes, int n_in,
                              void* d_out, int out_size, void* d_ws, size_t ws_size,
                              hipStream_t stream) {
  const float* inputs = (const float*)d_in[0];   // (B, 16) f32
  const float* weight = (const float*)d_in[1];   // (240,)  f32
  float* out = (float*)d_out;                    // (B, 16) f32
  const int B = in_sizes[0] / 16;
  qcir_kernel<<<B, 1024, 0, stream>>>(inputs, weight, out);
}